// Round 1
// 154.947 us; speedup vs baseline: 1.0316x; 1.0316x over previous
//
#include <hip/hip_runtime.h>
#include <stdint.h>

// HolographicFMLayer: out[b, p(i,j), n] = sum_m X[b,i,m] * X[b,j,(n-m)&63],
// pairs i<j of 24 fields, dim 64, batch 2048, fp32 in/out.
//
// R2 restructure: circular conv is commutative, so compute per-i the
// TRANSPOSED product D[n][j] = sum_k A[n][k] * B[k][j] with
//   A[n][k] = x_i[(n-k)&63]  (circulant windows from reversed-doubled r_i,
//                             funnel-shift gather; only 6 distinct windows
//                             cover all 8 (mt,ks) tiles since they depend on
//                             beta = 64+32ks-16mt in {16,32,48,64,80,96})
//   B[k][j] = X[j][k]        (contiguous-k fragments, loop-invariant/batch)
// MFMA C-layout (row=4q+r, col=ln) then gives each lane 4 CONSECUTIVE n at
// fixed j -> direct global_store_dwordx4; consecutive j -> consecutive pidx
// -> contiguous 256B output rows.
//
// R3 (this round): kill the rule-#20 scratch spill. bfrag was a 2D
// ext_vector array indexed by RUNTIME jt (loop lower bound jtlo is
// data-dependent) -> demoted to scratch -> ~170 MB of global-backed scratch
// reloads serialized in front of every MFMA cluster. Now: jt loop statically
// unrolled (uniform skip branch preserves the jtlo optimization), bfrag
// split into named 1-D arrays with unrolled ks, union punning replaced by
// __builtin_bit_cast, staging vectorized to float4/bf16x4, and
// __launch_bounds__(256,4) to pin >=4 blocks/CU.

typedef __bf16 bf16x8 __attribute__((ext_vector_type(8)));
typedef __bf16 bf16x4 __attribute__((ext_vector_type(4)));
typedef float  f32x4  __attribute__((ext_vector_type(4)));
typedef unsigned long long u64x2 __attribute__((ext_vector_type(2)));

#define NF       24
#define DIM      64
#define NPAIR    276
// r_i rows: 128 bf16 (256 B) + 8 B pad so ds_read_b64 at dw+2 (word 32) is
// in-bounds; 264 B keeps 8 B alignment per row.
#define RSTRIDE  264
#define XB_OFF   (NF * RSTRIDE)           // 6336 B, 16B-aligned
#define XB_STRIDE 72                       // elems; 144 B rows, 16B-aligned
#define LDS_BYTES (XB_OFF + 32 * XB_STRIDE * 2)   // 6336 + 4608 = 10944 B

__global__ __launch_bounds__(256, 4)
void holo_fm_kernel(const float* __restrict__ in, float* __restrict__ out)
{
    __shared__ __align__(16) unsigned char lds[LDS_BYTES];
    __bf16* xb = (__bf16*)(lds + XB_OFF);

    const int tid = threadIdx.x;
    const int b   = blockIdx.x;
    const float* xin = in + (size_t)b * (NF * DIM);

    // Zero B-pad rows 24..31 (jt=1 tile reads them; c there is masked).
    for (int e = tid; e < (32 - NF) * XB_STRIDE; e += 256)
        xb[NF * XB_STRIDE + e] = (__bf16)0.0f;

    // Stage (float4-vectorized): xb[j][k] = bf16(X[j][k]);
    // r_i[u] = bf16(X[i][(-u)&63]), doubled.
    for (int e4 = tid; e4 < (NF * DIM) / 4; e4 += 256) {
        int f = e4 >> 4;            // 16 float4 per field row
        int m = (e4 & 15) * 4;      // element offset, multiple of 4
        f32x4 v4 = *(const f32x4*)(xin + e4 * 4);
        __bf16 v0 = (__bf16)v4.x, v1 = (__bf16)v4.y,
               v2 = (__bf16)v4.z, v3 = (__bf16)v4.w;
        bf16x4 bv = {v0, v1, v2, v3};
        *(bf16x4*)(xb + f * XB_STRIDE + m) = bv;   // 8B-aligned ds_write_b64
        __bf16* rr = (__bf16*)(lds + f * RSTRIDE);
        int u0 = (64 - m) & 63;                    // for element m
        rr[u0]         = v0;  rr[u0 + 64]     = v0;
        rr[63 - m]     = v1;  rr[63 - m + 64] = v1;  // m+1 -> 63-m (m<=60)
        rr[62 - m]     = v2;  rr[62 - m + 64] = v2;
        rr[61 - m]     = v3;  rr[61 - m + 64] = v3;
    }
    __syncthreads();

    const int lane = tid & 63;
    const int wave = tid >> 6;
    const int ln   = lane & 15;   // B col j within tile / A row n within tile
    const int q    = lane >> 4;   // k-quad for A/B; n-row-quad for C/D

    // B fragments: B[k][j] = X[j][k]; lane holds k = 32ks + 8q + t, j-tile jt.
    // Named 1-D arrays + unrolled ks: ALL indices compile-time constant.
    bf16x8 bfrag0[2], bfrag1[2];
    #pragma unroll
    for (int ks = 0; ks < 2; ++ks) {
        bfrag0[ks] = *(const bf16x8*)(xb + ln        * XB_STRIDE + ks * 32 + q * 8);
        bfrag1[ks] = *(const bf16x8*)(xb + (16 + ln) * XB_STRIDE + ks * 32 + q * 8);
    }

    float* gbase = out + (size_t)b * NPAIR * DIM;

    // Each wave takes i = wave, wave+4, ... (i=23 has no pairs).
    for (int i = wave; i < NF - 1; i += 4) {
        const uint64_t* ri = (const uint64_t*)(lds + i * RSTRIDE);
        const int p0 = 23 * i - (i * (i - 1)) / 2;   // pidx of (i, i+1)

        // 6 distinct circulant A-windows: awin[w] covers beta = 16*(w+1).
        // A[n=16mt+ln][k=32ks+8q+t] = r_i[beta + 8q + t - ln], tile uses
        // awin[3 + 2*ks - mt].
        bf16x8 awin[6];
        #pragma unroll
        for (int w = 0; w < 6; ++w) {
            int ob = 2 * (16 * (w + 1) + 8 * q - ln);  // byte offset in [2,240]
            int dw = ob >> 3;
            int sh = (ob & 7) * 8;                      // 0/16/32/48 (lane-const)
            uint64_t w0 = ri[dw], w1 = ri[dw + 1], w2 = ri[dw + 2];
            uint64_t lo = (w0 >> sh) | ((w1 << 1) << (63 - sh));
            uint64_t hi = (w1 >> sh) | ((w2 << 1) << (63 - sh));
            u64x2 t; t.x = lo; t.y = hi;
            awin[w] = __builtin_bit_cast(bf16x8, t);
        }

        #pragma unroll
        for (int jt = 0; jt < 2; ++jt) {
            // jt=0 tile has no j>i lanes once i>=15: uniform skip (was jtlo).
            if (jt == 0 && i >= 15) continue;
            const int j = 16 * jt + ln;
            const bool valid = (j > i) & (j < NF);
            float* orow = gbase + ((size_t)(p0 + j - i - 1)) * DIM + 4 * q;
            #pragma unroll
            for (int mt = 0; mt < 4; ++mt) {
                f32x4 c = {0.f, 0.f, 0.f, 0.f};
                c = __builtin_amdgcn_mfma_f32_16x16x32_bf16(
                        awin[3 - mt], jt ? bfrag1[0] : bfrag0[0], c, 0, 0, 0);
                c = __builtin_amdgcn_mfma_f32_16x16x32_bf16(
                        awin[5 - mt], jt ? bfrag1[1] : bfrag0[1], c, 0, 0, 0);
                if (valid)
                    *(f32x4*)(orow + 16 * mt) = c;   // n = 16mt + 4q .. +3
            }
        }
    }
}

extern "C" void kernel_launch(void* const* d_in, const int* in_sizes, int n_in,
                              void* d_out, int out_size, void* d_ws, size_t ws_size,
                              hipStream_t stream)
{
    const float* in  = (const float*)d_in[0];
    float*       out = (float*)d_out;
    const int batches = in_sizes[0] / (NF * DIM);   // 2048
    holo_fm_kernel<<<dim3(batches), dim3(256), 0, stream>>>(in, out);
}

// Round 2
// 154.034 us; speedup vs baseline: 1.0378x; 1.0059x over previous
//
#include <hip/hip_runtime.h>
#include <stdint.h>

// HolographicFMLayer: out[b, p(i,j), n] = sum_m X[b,i,m] * X[b,j,(n-m)&63],
// pairs i<j of 24 fields, dim 64, batch 2048, fp32 in/out.
//
// R2: per-i transposed MFMA  D[n][j] = sum_k A[n][k]*B[k][j], A = circulant
//     windows of reversed row r_i, B[k][j] = X[j][k]; C-layout gives each
//     lane 4 consecutive n at fixed j -> direct global_store_dwordx4.
// R3: static jt unroll / named bfrag arrays / float4 staging (+5 us).
// R4 (this round): kill the per-iter funnel-shift dependency chain.
//     The per-lane byte shift depends only on ln&3 -> only 4 distinct
//     byte-rotations of r_i exist. Build them ONCE per block in LDS
//     (pass 2, cooperative), then each A-window is just 2 aligned
//     ds_read_b64 with immediate offsets feeding MFMA directly:
//     ~60 VALU/iter removed, dep chain ds_read->shift*10->MFMA becomes
//     ds_read->MFMA. Copies laid out at 288B sub-row stride so the four
//     ln&3 groups occupy different bank quadrants (~4 dwords/bank, the
//     wave64 b64 minimum). LDS 10.9->31.5 KB (still 5 blocks/CU).

typedef __bf16 bf16x8 __attribute__((ext_vector_type(8)));
typedef __bf16 bf16x4 __attribute__((ext_vector_type(4)));
typedef float  f32x4  __attribute__((ext_vector_type(4)));
typedef unsigned long long u64x2 __attribute__((ext_vector_type(2)));

#define NF       24
#define DIM      64
#define NPAIR    276

// xb: B-operand rows, [32][XB_STRIDE] bf16 (rows 24..31 zero pad)
#define XB_STRIDE 72                       // elems; 144 B rows, 16B-aligned
#define XB_BYTES  (32 * XB_STRIDE * 2)     // 4608 B
#define COPY_OFF  XB_BYTES                 // copies region, 16B-aligned
// Per field f: 4 sub-rows at 288 B stride.
//   c=0: r_ext[u] = x_f[(-u)&63], u in [0,132)  (264 B used of 288)
//   c=1..3: row_c[u] = r[u+c],    u in [0,128)  (256 B used of 288)
// Window read: lane (q,ln) uses c=(4-(ln&3))&3, elem0 = 16+8q-ln-c (mult of
// 4, >=0), reads elements [elem0+16w, +8) of its row = r[16(w+1)+8q-ln ...]
// == the R3 funnel result, bit-identical.
#define FSTRIDE   1120                     // 4*288 - 32; mult of 16
#define LDS_BYTES (COPY_OFF + NF * FSTRIDE)   // 4608 + 26880 = 31488 B

__global__ __launch_bounds__(256, 5)
void holo_fm_kernel(const float* __restrict__ in, float* __restrict__ out)
{
    __shared__ __align__(16) unsigned char lds[LDS_BYTES];
    __bf16* xb = (__bf16*)lds;

    const int tid = threadIdx.x;
    const int b   = blockIdx.x;
    const float* xin = in + (size_t)b * (NF * DIM);

    // Zero B-pad rows 24..31 (jt=1 tile reads them; c there is masked).
    for (int e = tid; e < (32 - NF) * XB_STRIDE; e += 256)
        xb[NF * XB_STRIDE + e] = (__bf16)0.0f;

    // Pass 1: xb[j][k] = bf16(X[j][k]);  r_ext[u] = bf16(X[f][(-u)&63]),
    // u in [0,132) (doubled + 4-elem wrap tail for pass-2 reads).
    for (int e4 = tid; e4 < (NF * DIM) / 4; e4 += 256) {
        int f = e4 >> 4;            // 16 float4 per field row
        int m = (e4 & 15) * 4;      // element offset, multiple of 4
        f32x4 v4 = *(const f32x4*)(xin + e4 * 4);
        __bf16 vv0 = (__bf16)v4.x, vv1 = (__bf16)v4.y,
               vv2 = (__bf16)v4.z, vv3 = (__bf16)v4.w;
        bf16x4 bv = {vv0, vv1, vv2, vv3};
        *(bf16x4*)(xb + f * XB_STRIDE + m) = bv;   // 8B-aligned ds_write_b64
        __bf16* rr = (__bf16*)(lds + COPY_OFF + f * FSTRIDE);
        __bf16 vk[4] = {vv0, vv1, vv2, vv3};
        #pragma unroll
        for (int k = 0; k < 4; ++k) {
            int u = (64 - (m + k)) & 63;
            rr[u]      = vk[k];
            rr[u + 64] = vk[k];
            if (u < 4) rr[u + 128] = vk[k];        // wrap tail
        }
    }
    __syncthreads();

    // Pass 2: build the 3 byte-shifted copies per field from r_ext.
    // row_c bytes [16k,16k+16) = r_ext bytes [16k+2c, 16k+2c+16).
    for (int t = tid; t < NF * 3 * 16; t += 256) {   // 1152 chunks
        int f  = t / 48;
        int r  = t - f * 48;
        int cc = (r >> 4) + 1;                       // 1..3
        int k  = r & 15;
        unsigned char* fb = lds + COPY_OFF + f * FSTRIDE;
        const uint64_t* rx = (const uint64_t*)fb;
        uint64_t A  = rx[2 * k];
        uint64_t B  = rx[2 * k + 1];
        uint64_t C2 = rx[2 * k + 2];
        int sh = cc << 4;                            // 16/32/48, never 0
        uint64_t lo = (A >> sh) | (B  << (64 - sh));
        uint64_t hi = (B >> sh) | (C2 << (64 - sh));
        u64x2 w2; w2.x = lo; w2.y = hi;
        *(u64x2*)(fb + 288 * cc + 16 * k) = w2;      // 16B-aligned b128
    }

    const int lane = tid & 63;
    const int wave = tid >> 6;
    const int ln   = lane & 15;   // B col j within tile / A row n within tile
    const int q    = lane >> 4;   // k-quad for A/B; n-row-quad for C/D

    // B fragments (xb ready since first sync): B[k][j] = X[j][k];
    // lane holds k = 32ks + 8q + t. Static indices only.
    bf16x8 bfrag0[2], bfrag1[2];
    #pragma unroll
    for (int ks = 0; ks < 2; ++ks) {
        bfrag0[ks] = *(const bf16x8*)(xb + ln        * XB_STRIDE + ks * 32 + q * 8);
        bfrag1[ks] = *(const bf16x8*)(xb + (16 + ln) * XB_STRIDE + ks * 32 + q * 8);
    }
    __syncthreads();

    // Per-lane window base: copy row c, element offset elem0 (byte 2*elem0,
    // 8B-aligned since ln+c ≡ 0 mod 4).
    const int cc    = (4 - (ln & 3)) & 3;
    const int elem0 = 16 + 8 * q - ln - cc;
    const unsigned char* abase = lds + COPY_OFF + 288 * cc + 2 * elem0;

    float* gbase = out + (size_t)b * NPAIR * DIM;

    // Each wave takes i = wave, wave+4, ... (i=23 has no pairs).
    for (int i = wave; i < NF - 1; i += 4) {
        const unsigned char* ap = abase + i * FSTRIDE;
        const int p0 = 23 * i - (i * (i - 1)) / 2;   // pidx of (i, i+1)

        // 6 circulant A-windows: pure LDS reads, immediate offsets.
        bf16x8 awin[6];
        #pragma unroll
        for (int w = 0; w < 6; ++w) {
            uint64_t lo = *(const uint64_t*)(ap + 32 * w);
            uint64_t hi = *(const uint64_t*)(ap + 32 * w + 8);
            u64x2 t2; t2.x = lo; t2.y = hi;
            awin[w] = __builtin_bit_cast(bf16x8, t2);
        }

        #pragma unroll
        for (int jt = 0; jt < 2; ++jt) {
            // jt=0 tile has no j>i lanes once i>=15: uniform skip.
            if (jt == 0 && i >= 15) continue;
            const int j = 16 * jt + ln;
            const bool valid = (j > i) & (j < NF);
            float* orow = gbase + ((size_t)(p0 + j - i - 1)) * DIM + 4 * q;
            #pragma unroll
            for (int mt = 0; mt < 4; ++mt) {
                f32x4 c = {0.f, 0.f, 0.f, 0.f};
                c = __builtin_amdgcn_mfma_f32_16x16x32_bf16(
                        awin[3 - mt], jt ? bfrag1[0] : bfrag0[0], c, 0, 0, 0);
                c = __builtin_amdgcn_mfma_f32_16x16x32_bf16(
                        awin[5 - mt], jt ? bfrag1[1] : bfrag0[1], c, 0, 0, 0);
                if (valid)
                    *(f32x4*)(orow + 16 * mt) = c;   // n = 16mt + 4q .. +3
            }
        }
    }
}

extern "C" void kernel_launch(void* const* d_in, const int* in_sizes, int n_in,
                              void* d_out, int out_size, void* d_ws, size_t ws_size,
                              hipStream_t stream)
{
    const float* in  = (const float*)d_in[0];
    float*       out = (float*)d_out;
    const int batches = in_sizes[0] / (NF * DIM);   // 2048
    holo_fm_kernel<<<dim3(batches), dim3(256), 0, stream>>>(in, out);
}

// Round 3
// 152.900 us; speedup vs baseline: 1.0455x; 1.0074x over previous
//
#include <hip/hip_runtime.h>
#include <stdint.h>

// HolographicFMLayer: out[b, p(i,j), n] = sum_m X[b,i,m] * X[b,j,(n-m)&63],
// pairs i<j of 24 fields, dim 64, batch 2048, fp32 in/out.
//
// R2: per-i transposed MFMA  D[n][j] = sum_k A[n][k]*B[k][j], A = circulant
//     windows of reversed row r_i, B[k][j] = X[j][k].
// R3: static jt unroll / named bfrag arrays / float4 staging (+5 us).
// R4: precomputed byte-rotated r_i copies -> windows are 2 ds_read_b64 (null).
// R5 (this round): fix the STORE pattern. The direct C-layout store wrote
//     16 scattered 64 B half-line segments per instruction (lanes stride
//     256 B) -> write path at ~1/3 efficiency, matching the observed ~67 us
//     vs the 23 us write roofline. Now each wave transposes its 16-row x
//     128 B half-tile through a 2 KB XOR-swizzled LDS bounce (conflict-free
//     b128 both sides, verified by bank arithmetic) and stores 8 x 128 B
//     FULL cache lines per instruction, 8 lanes contiguous per row. Also
//     uniformly skips dead store groups (jt0/s0 for i>=7, jt1/s1 always).
//     LDS 31.5 -> 38.8 KB, still 4 blocks/CU.

typedef __bf16 bf16x8 __attribute__((ext_vector_type(8)));
typedef __bf16 bf16x4 __attribute__((ext_vector_type(4)));
typedef float  f32x4  __attribute__((ext_vector_type(4)));
typedef unsigned long long u64x2 __attribute__((ext_vector_type(2)));

#define NF       24
#define DIM      64
#define NPAIR    276

// xb: B-operand rows, [32][XB_STRIDE] bf16 (rows 24..31 zero pad)
#define XB_STRIDE 72                       // elems; 144 B rows, 16B-aligned
#define XB_BYTES  (32 * XB_STRIDE * 2)     // 4608 B
#define COPY_OFF  XB_BYTES
// Per field f: 4 sub-rows at 288 B stride (c=0 reversed-doubled row r_ext,
// c=1..3 byte-rotated copies). Window read for lane (q,ln): copy
// c=(4-(ln&3))&3, elem0=16+8q-ln-c, elements [elem0+16w, +8).
#define FSTRIDE   1120                     // 4*288 - 32; mult of 16
#define BOUNCE_OFF (COPY_OFF + NF * FSTRIDE)   // 4608 + 26880 = 31488
#define LDS_BYTES  (BOUNCE_OFF + 4 * 2048)     // + 8 KB bounce = 39680 B

__global__ __launch_bounds__(256, 4)
void holo_fm_kernel(const float* __restrict__ in, float* __restrict__ out)
{
    __shared__ __align__(16) unsigned char lds[LDS_BYTES];
    __bf16* xb = (__bf16*)lds;

    const int tid = threadIdx.x;
    const int b   = blockIdx.x;
    const float* xin = in + (size_t)b * (NF * DIM);

    // Zero B-pad rows 24..31 (jt=1 tile reads them; result there unread).
    for (int e = tid; e < (32 - NF) * XB_STRIDE; e += 256)
        xb[NF * XB_STRIDE + e] = (__bf16)0.0f;

    // Pass 1: xb[j][k] = bf16(X[j][k]);  r_ext[u] = bf16(X[f][(-u)&63]),
    // u in [0,132) (doubled + 4-elem wrap tail for pass-2 reads).
    for (int e4 = tid; e4 < (NF * DIM) / 4; e4 += 256) {
        int f = e4 >> 4;            // 16 float4 per field row
        int m = (e4 & 15) * 4;      // element offset, multiple of 4
        f32x4 v4 = *(const f32x4*)(xin + e4 * 4);
        __bf16 vv0 = (__bf16)v4.x, vv1 = (__bf16)v4.y,
               vv2 = (__bf16)v4.z, vv3 = (__bf16)v4.w;
        bf16x4 bv = {vv0, vv1, vv2, vv3};
        *(bf16x4*)(xb + f * XB_STRIDE + m) = bv;   // 8B-aligned ds_write_b64
        __bf16* rr = (__bf16*)(lds + COPY_OFF + f * FSTRIDE);
        __bf16 vk[4] = {vv0, vv1, vv2, vv3};
        #pragma unroll
        for (int k = 0; k < 4; ++k) {
            int u = (64 - (m + k)) & 63;
            rr[u]      = vk[k];
            rr[u + 64] = vk[k];
            if (u < 4) rr[u + 128] = vk[k];        // wrap tail
        }
    }
    __syncthreads();

    // Pass 2: build the 3 byte-shifted copies per field from r_ext.
    for (int t = tid; t < NF * 3 * 16; t += 256) {   // 1152 chunks
        int f  = t / 48;
        int r  = t - f * 48;
        int cc = (r >> 4) + 1;                       // 1..3
        int k  = r & 15;
        unsigned char* fb = lds + COPY_OFF + f * FSTRIDE;
        const uint64_t* rx = (const uint64_t*)fb;
        uint64_t A  = rx[2 * k];
        uint64_t B  = rx[2 * k + 1];
        uint64_t C2 = rx[2 * k + 2];
        int sh = cc << 4;                            // 16/32/48, never 0
        uint64_t lo = (A >> sh) | (B  << (64 - sh));
        uint64_t hi = (B >> sh) | (C2 << (64 - sh));
        u64x2 w2; w2.x = lo; w2.y = hi;
        *(u64x2*)(fb + 288 * cc + 16 * k) = w2;      // 16B-aligned b128
    }

    const int lane = tid & 63;
    const int wave = tid >> 6;
    const int ln   = lane & 15;   // B col j within tile / A row n within tile
    const int q    = lane >> 4;   // k-quad for A/B; n-row-quad for C/D

    // B fragments (xb ready since first sync). Static indices only.
    bf16x8 bfrag0[2], bfrag1[2];
    #pragma unroll
    for (int ks = 0; ks < 2; ++ks) {
        bfrag0[ks] = *(const bf16x8*)(xb + ln        * XB_STRIDE + ks * 32 + q * 8);
        bfrag1[ks] = *(const bf16x8*)(xb + (16 + ln) * XB_STRIDE + ks * 32 + q * 8);
    }
    __syncthreads();

    // Per-lane window base.
    const int cc    = (4 - (ln & 3)) & 3;
    const int elem0 = 16 + 8 * q - ln - cc;
    const unsigned char* abase = lds + COPY_OFF + 288 * cc + 2 * elem0;

    // Per-wave 2 KB bounce buffer (16 rows x 128 B), XOR-swizzled.
    // Write (lane q,ln; sub-col u in {0,1}): dword (ln*32 + u*16 + q*4)
    //   ^ ((ln&7)<<2). u lives in bit 4, disjoint from the rest, so
    //   addr(u=1) = addr(u=0) ^ 64 bytes. 8 dwords/bank -> conflict-free.
    // Read (lane l, group s): dword ((l>>3)*32 + (l&7)*4) ^ ((l>>3)<<2),
    //   + s*1024 bytes. Also 8 dwords/bank -> conflict-free.
    unsigned char* wb = lds + BOUNCE_OFF + wave * 2048;
    const int w_off0 = ((ln * 32 + q * 4) ^ ((ln & 7) << 2)) << 2;
    const int w_off1 = w_off0 ^ 64;
    const int r_off  = (((lane >> 3) * 32 + (lane & 7) * 4) ^ ((lane >> 3) << 2)) << 2;
    const int g8     = lane >> 3;    // row group within store
    const int w8     = lane & 7;     // 16 B column within 128 B segment

    float* gbase = out + (size_t)b * NPAIR * DIM;

    // Each wave takes i = wave, wave+4, ... (i=23 has no pairs).
    for (int i = wave; i < NF - 1; i += 4) {
        const unsigned char* ap = abase + i * FSTRIDE;
        const int p0 = 23 * i - (i * (i - 1)) / 2;   // pidx of (i, i+1)

        // 6 circulant A-windows: pure LDS reads, immediate offsets.
        bf16x8 awin[6];
        #pragma unroll
        for (int w = 0; w < 6; ++w) {
            uint64_t lo = *(const uint64_t*)(ap + 32 * w);
            uint64_t hi = *(const uint64_t*)(ap + 32 * w + 8);
            u64x2 t2; t2.x = lo; t2.y = hi;
            awin[w] = __builtin_bit_cast(bf16x8, t2);
        }

        #pragma unroll
        for (int jt = 0; jt < 2; ++jt) {
            if (jt == 0 && i >= 15) continue;   // no j>i lanes left
            #pragma unroll
            for (int h = 0; h < 2; ++h) {
                // mt = 2h (u=0) and 2h+1 (u=1): n in [32h, 32h+32).
                f32x4 c0 = {0.f, 0.f, 0.f, 0.f};
                f32x4 c1 = {0.f, 0.f, 0.f, 0.f};
                c0 = __builtin_amdgcn_mfma_f32_16x16x32_bf16(
                        awin[3 - 2 * h], jt ? bfrag1[0] : bfrag0[0], c0, 0, 0, 0);
                c0 = __builtin_amdgcn_mfma_f32_16x16x32_bf16(
                        awin[5 - 2 * h], jt ? bfrag1[1] : bfrag0[1], c0, 0, 0, 0);
                c1 = __builtin_amdgcn_mfma_f32_16x16x32_bf16(
                        awin[2 - 2 * h], jt ? bfrag1[0] : bfrag0[0], c1, 0, 0, 0);
                c1 = __builtin_amdgcn_mfma_f32_16x16x32_bf16(
                        awin[4 - 2 * h], jt ? bfrag1[1] : bfrag0[1], c1, 0, 0, 0);

                // Transpose bounce: rows = j-within-tile, 32 floats each.
                *(f32x4*)(wb + w_off0) = c0;
                *(f32x4*)(wb + w_off1) = c1;

                #pragma unroll
                for (int s = 0; s < 2; ++s) {
                    if (jt == 1 && s == 1) continue;         // rows 24..31 dead
                    if (jt == 0 && s == 0 && i >= 7) continue; // j<=7 all <=i
                    f32x4 v = *(const f32x4*)(wb + r_off + s * 1024);
                    const int jrow = 16 * jt + 8 * s + g8;
                    if (jrow > i) {
                        float* dst = gbase
                            + (size_t)(p0 + jrow - i - 1) * DIM
                            + 32 * h + 4 * w8;
                        *(f32x4*)dst = v;   // 8 lanes x 16 B = full 128 B line
                    }
                }
            }
        }
    }
}

extern "C" void kernel_launch(void* const* d_in, const int* in_sizes, int n_in,
                              void* d_out, int out_size, void* d_ws, size_t ws_size,
                              hipStream_t stream)
{
    const float* in  = (const float*)d_in[0];
    float*       out = (float*)d_out;
    const int batches = in_sizes[0] / (NF * DIM);   // 2048
    holo_fm_kernel<<<dim3(batches), dim3(256), 0, stream>>>(in, out);
}